// Round 1
// baseline (251.077 us; speedup 1.0000x reference)
//
#include <hip/hip_runtime.h>
#include <math.h>

// gauss_order G=7, Q=49. B = B1*B2 = 524288 for the reference shapes,
// but we derive B from in_sizes at launch.
#define LOG2PI_F 1.8378770664093453f

// Part B first (blockIdx < partB_blocks): one thread per pair -> integral.
// Part A after: one thread per (pair,q) -> gauss_pts, perfectly coalesced
// float2 stores (8 B/lane). Part B scheduled first so its input reads
// overlap part A's dominant write stream.
__global__ __launch_bounds__(256) void gauss2d_kernel(
    const float* __restrict__ tv_means,     // [B,2]
    const float* __restrict__ tv_covars,    // [B,2,2]
    const float* __restrict__ rotations,    // [B,2,2]
    const float* __restrict__ translations, // [B,2]
    const float* __restrict__ eta,          // [2,49]
    const float* __restrict__ weights,      // [49]
    float* __restrict__ gauss_pts,          // [B,49,2]
    float* __restrict__ integral,           // [B]
    unsigned int B,
    unsigned int partB_blocks)
{
    const unsigned int Q = 49u;

    if (blockIdx.x < partB_blocks) {
        // ---- integral: one thread per pair ----
        unsigned int p = blockIdx.x * 256u + threadIdx.x;
        if (p >= B) return;

        const float4 R  = ((const float4*)rotations)[p];     // R00,R01,R10,R11
        const float2 tr = ((const float2*)translations)[p];
        const float2 mu = ((const float2*)tv_means)[p];
        const float4 C  = ((const float4*)tv_covars)[p];     // c00,c01,c10,c11

        float det     = C.x * C.w - C.y * C.z;
        float inv_det = 1.0f / det;
        float lognorm = fmaf(-0.5f, __logf(det), -LOG2PI_F);
        float c01p10  = C.y + C.z;

        float s = 0.0f;
        #pragma unroll 7
        for (int q = 0; q < 49; ++q) {
            float ex = eta[q];
            float ey = eta[49 + q];
            float gx = fmaf(R.x, ex, fmaf(R.y, ey, tr.x));
            float gy = fmaf(R.z, ex, fmaf(R.w, ey, tr.y));
            float dx = gx - mu.x;
            float dy = gy - mu.y;
            float quad = (C.w * dx * dx - c01p10 * dx * dy + C.x * dy * dy) * inv_det;
            s += weights[q] * __expf(fmaf(-0.5f, quad, lognorm));
        }
        integral[p] = fminf(fmaxf(s, 0.0f), 1.0f);
    } else {
        // ---- gauss_pts: one thread per (pair,q), coalesced float2 store ----
        unsigned int t = (blockIdx.x - partB_blocks) * 256u + threadIdx.x; // < B*49
        unsigned int pair = t / Q;              // magic-mul, constant divisor
        unsigned int q    = t - pair * Q;
        if (pair >= B) return;

        const float4 R  = ((const float4*)rotations)[pair];
        const float2 tr = ((const float2*)translations)[pair];
        float ex = eta[q];
        float ey = eta[49 + q];
        float gx = fmaf(R.x, ex, fmaf(R.y, ey, tr.x));
        float gy = fmaf(R.z, ex, fmaf(R.w, ey, tr.y));
        ((float2*)gauss_pts)[t] = make_float2(gx, gy);
    }
}

extern "C" void kernel_launch(void* const* d_in, const int* in_sizes, int n_in,
                              void* d_out, int out_size, void* d_ws, size_t ws_size,
                              hipStream_t stream) {
    const float* tv_means     = (const float*)d_in[0];
    const float* tv_covars    = (const float*)d_in[1];
    const float* rotations    = (const float*)d_in[2];
    const float* translations = (const float*)d_in[3];
    const float* eta          = (const float*)d_in[4];
    const float* weights      = (const float*)d_in[5];

    const unsigned int B = (unsigned int)(in_sizes[0] / 2);   // [B,2] means
    float* gauss_pts = (float*)d_out;                          // first B*98 floats
    float* integral  = (float*)d_out + (size_t)B * 98u;        // then B floats

    const unsigned int partB_blocks = (B + 255u) / 256u;
    const unsigned int partA_blocks = (unsigned int)(((size_t)B * 49u + 255u) / 256u);

    dim3 grid(partA_blocks + partB_blocks);
    dim3 block(256);
    hipLaunchKernelGGL(gauss2d_kernel, grid, block, 0, stream,
                       tv_means, tv_covars, rotations, translations,
                       eta, weights, gauss_pts, integral, B, partB_blocks);
}